// Round 6
// baseline (1056.899 us; speedup 1.0000x reference)
//
#include <hip/hip_runtime.h>

// Problem constants
#define NTOK 65536          // B*S tokens
#define DDIM 64             // embedding dim
#define KCB  4096           // codebook size
#define MB   128            // tokens per block
#define NCH  128            // codes per staged chunk
#define NCHUNKS (KCB / NCH) // 32
#define ESTR 72             // padded LDS row stride (bf16 elems); 144B rows -> 16B aligned
#define WWIN 3.0e-5f        // rescore window >= 2*(ulp(64) + mfma-vs-chain err) ~ 1.7e-5
#define IDXOFF  (NTOK * DDIM)
#define LOSSOFF (NTOK * DDIM + NTOK)

// Workspace layout (bytes)
#define OFF_E2   0u           // 4096 f32
#define OFF_EH   16384u       // 4096*64 bf16-high (u16)
#define OFF_EL   540672u      // bf16-low
#define OFF_Z2   1064960u     // 65536 f32
#define OFF_KEYS 1327104u     // 65536 u64
#define OFF_MISC 1851392u     // [0]=lossacc(double), [8]=gcount(u32)
#define OFF_LIST 1851904u     // u32 entries: (token<<12)|n

typedef __bf16 bf16x8 __attribute__((ext_vector_type(8)));
typedef float  f32x4  __attribute__((ext_vector_type(4)));

__device__ __forceinline__ float opaque(float x) { asm volatile("" : "+v"(x)); return x; }

// numpy pairwise sum of squares, n=64
__device__ __forceinline__ float np_sumsq64(const float* __restrict__ v) {
    float r[8];
#pragma unroll
    for (int j = 0; j < 8; ++j) r[j] = opaque(v[j] * v[j]);
#pragma unroll
    for (int i = 1; i < 8; ++i)
#pragma unroll
        for (int j = 0; j < 8; ++j) r[j] += opaque(v[8 * i + j] * v[8 * i + j]);
    return ((r[0] + r[1]) + (r[2] + r[3])) + ((r[4] + r[5]) + (r[6] + r[7]));
}

__device__ __forceinline__ unsigned short bf16rne(float x) {
    unsigned u = __float_as_uint(x);
    return (unsigned short)((u + 0x7fffu + ((u >> 16) & 1u)) >> 16);
}
__device__ __forceinline__ float bf16tof(unsigned short h) {
    return __uint_as_float(((unsigned)h) << 16);
}

// ---- Init: keys=+inf, loss=0, count=0 ----
__global__ void k_init(unsigned long long* __restrict__ keys,
                       double* __restrict__ lossacc, unsigned* __restrict__ gcount) {
    int i = blockIdx.x * blockDim.x + threadIdx.x;
    if (i < NTOK) keys[i] = 0xFFFFFFFFFFFFFFFFull;
    if (i == 0) { *lossacc = 0.0; *gcount = 0u; }
}

// ---- Prep: e2 (np pairwise) + split-bf16 codebook ----
__global__ void k_prep(const float* __restrict__ emb, float* __restrict__ e2,
                       unsigned short* __restrict__ eh, unsigned short* __restrict__ el) {
    int k = blockIdx.x * blockDim.x + threadIdx.x;
    if (k >= KCB) return;
    float row[DDIM];
    const float4* r4 = (const float4*)(emb + (size_t)k * DDIM);
#pragma unroll
    for (int i = 0; i < DDIM / 4; ++i) {
        float4 v = r4[i];
        row[4*i+0] = v.x; row[4*i+1] = v.y; row[4*i+2] = v.z; row[4*i+3] = v.w;
    }
    e2[k] = np_sumsq64(row);
#pragma unroll
    for (int j = 0; j < DDIM; ++j) {
        unsigned short h = bf16rne(row[j]);
        unsigned short l = bf16rne(row[j] - bf16tof(h));
        eh[(size_t)k * DDIM + j] = h;
        el[(size_t)k * DDIM + j] = l;
    }
}

// ---- Main: two MFMA sweeps; sweep0 min, sweep1 append near-ties to global list ----
// 512 thr = 8 waves; wm = w>>1 (0..3): 32-token group; wn = w&1: 64-code half.
// A-fragments (z side) hoisted in VGPRs for the whole kernel (z block-invariant).
__global__ __launch_bounds__(512, 4) void k_vq(
    const float* __restrict__ z,
    const float* __restrict__ e2g,
    const unsigned short* __restrict__ ehg, const unsigned short* __restrict__ elg,
    float* __restrict__ z2g,
    unsigned* __restrict__ list, unsigned* __restrict__ gcount, unsigned lcap) {
    __shared__ alignas(16) unsigned short zsh[MB * ESTR], zsl[MB * ESTR];
    __shared__ alignas(16) unsigned short esh[NCH * ESTR], esl[NCH * ESTR];
    __shared__ float z2s[MB];
    __shared__ float e2t[NCH];
    __shared__ unsigned v0u[MB];

    const int tid  = threadIdx.x;
    const int lane = tid & 63;
    const int l15  = lane & 15;
    const int quad = lane >> 4;
    const int w    = tid >> 6;
    const int wm   = w >> 1;    // 0..3
    const int wn   = w & 1;     // 0..1
    const size_t zbase = (size_t)blockIdx.x * MB * DDIM;
    const int tok0 = blockIdx.x * MB;

    if (tid < MB) v0u[tid] = 0x7f800000u;

    // ---- Stage z: fp32 -> doubled split-bf16 LDS [m][k] ----
#pragma unroll
    for (int it = 0; it < 4; ++it) {
        int f  = it * 512 + tid;    // 0..2047 float4 slots
        int rr = f >> 4, c4 = f & 15;
        float4 v = ((const float4*)(z + zbase))[f];
        float d[4] = {v.x + v.x, v.y + v.y, v.z + v.z, v.w + v.w};  // exact 2*z
        ushort4 hh, ll;
        unsigned short h;
        h = bf16rne(d[0]); hh.x = h; ll.x = bf16rne(d[0] - bf16tof(h));
        h = bf16rne(d[1]); hh.y = h; ll.y = bf16rne(d[1] - bf16tof(h));
        h = bf16rne(d[2]); hh.z = h; ll.z = bf16rne(d[2] - bf16tof(h));
        h = bf16rne(d[3]); hh.w = h; ll.w = bf16rne(d[3] - bf16tof(h));
        *(ushort4*)(zsh + rr * ESTR + c4 * 4) = hh;
        *(ushort4*)(zsl + rr * ESTR + c4 * 4) = ll;
    }
    // z2 per token: exact np pairwise (from global z, independent of zsh)
    if (tid < MB) {
        float row[DDIM];
        const float4* zr4 = (const float4*)(z + zbase + (size_t)tid * DDIM);
#pragma unroll
        for (int i = 0; i < DDIM / 4; ++i) {
            float4 v = zr4[i];
            row[4*i+0] = v.x; row[4*i+1] = v.y; row[4*i+2] = v.z; row[4*i+3] = v.w;
        }
        float s = np_sumsq64(row);
        z2s[tid] = s;
        z2g[tok0 + tid] = s;
    }
    __syncthreads();

    // ---- Hoist A-fragments (whole-kernel live) + z2 ----
    bf16x8 Ah[2][2], Al[2][2];   // [ms][khalf]
    f32x4  z2l[2];
#pragma unroll
    for (int ms = 0; ms < 2; ++ms) {
        int ml = wm * 32 + ms * 16 + l15;
        const unsigned short* ph = zsh + ml * ESTR + quad * 8;
        const unsigned short* pl = zsl + ml * ESTR + quad * 8;
        Ah[ms][0] = *(const bf16x8*)(ph);
        Ah[ms][1] = *(const bf16x8*)(ph + 32);
        Al[ms][0] = *(const bf16x8*)(pl);
        Al[ms][1] = *(const bf16x8*)(pl + 32);
        z2l[ms]   = *(const f32x4*)(z2s + wm * 32 + ms * 16 + quad * 4);
    }

    float vrun[8];
#pragma unroll
    for (int i = 0; i < 8; ++i) vrun[i] = 3.0e38f;
    float vl[2][4];

#pragma unroll 1
    for (int phase = 0; phase < 2; ++phase) {
#pragma unroll 1
        for (int ch = 0; ch < NCHUNKS; ++ch) {
            const int n0 = ch * NCH;
            __syncthreads();   // prior chunk frag reads done
#pragma unroll
            for (int it = 0; it < 4; ++it) {
                int f  = it * 512 + tid;    // 0..2047 ushort4 slots (128 rows * 16)
                int rr = f >> 4, c4 = f & 15;
                *(ushort4*)(esh + rr * ESTR + c4 * 4) =
                    ((const ushort4*)(ehg + (size_t)(n0 + rr) * DDIM))[c4];
                *(ushort4*)(esl + rr * ESTR + c4 * 4) =
                    ((const ushort4*)(elg + (size_t)(n0 + rr) * DDIM))[c4];
            }
            if (tid < NCH) e2t[tid] = e2g[n0 + tid];
            __syncthreads();

#pragma unroll
            for (int ns = 0; ns < 4; ++ns) {
                int nl = wn * 64 + ns * 16 + l15;
                const unsigned short* pb = esh + nl * ESTR + quad * 8;
                const unsigned short* pc = esl + nl * ESTR + quad * 8;
                bf16x8 Bh0 = *(const bf16x8*)(pb);
                bf16x8 Bh1 = *(const bf16x8*)(pb + 32);
                bf16x8 Bl0 = *(const bf16x8*)(pc);
                bf16x8 Bl1 = *(const bf16x8*)(pc + 32);
                float e2v = e2t[nl];
                int   n   = n0 + nl;
#pragma unroll
                for (int ms = 0; ms < 2; ++ms) {
                    // two independent 3-MFMA chains (latency), summed in VALU
                    f32x4 a0 = {0.f, 0.f, 0.f, 0.f}, a1 = {0.f, 0.f, 0.f, 0.f};
                    a0 = __builtin_amdgcn_mfma_f32_16x16x32_bf16(Ah[ms][0], Bh0, a0, 0, 0, 0);
                    a1 = __builtin_amdgcn_mfma_f32_16x16x32_bf16(Ah[ms][1], Bh1, a1, 0, 0, 0);
                    a0 = __builtin_amdgcn_mfma_f32_16x16x32_bf16(Ah[ms][0], Bl0, a0, 0, 0, 0);
                    a1 = __builtin_amdgcn_mfma_f32_16x16x32_bf16(Ah[ms][1], Bl1, a1, 0, 0, 0);
                    a0 = __builtin_amdgcn_mfma_f32_16x16x32_bf16(Al[ms][0], Bh0, a0, 0, 0, 0);
                    a1 = __builtin_amdgcn_mfma_f32_16x16x32_bf16(Al[ms][1], Bh1, a1, 0, 0, 0);
#pragma unroll
                    for (int r = 0; r < 4; ++r) {
                        float shat = (z2l[ms][r] + e2v) - (a0[r] + a1[r]);
                        if (phase == 0) {
                            vrun[ms * 4 + r] = fminf(vrun[ms * 4 + r], shat);
                        } else if (shat <= vl[ms][r]) {
                            int m = wm * 32 + ms * 16 + quad * 4 + r;
                            unsigned idx = atomicAdd(gcount, 1u);
                            if (idx < lcap)
                                list[idx] = ((unsigned)(tok0 + m) << 12) | (unsigned)n;
                        }
                    }
                }
            }
        }
        if (phase == 0) {
            // commit per-token mins across the 16 n-lanes, then LDS atomicMin
#pragma unroll
            for (int vi = 0; vi < 8; ++vi) {
                float v = vrun[vi];
                v = fminf(v, __shfl_xor(v, 1));
                v = fminf(v, __shfl_xor(v, 2));
                v = fminf(v, __shfl_xor(v, 4));
                v = fminf(v, __shfl_xor(v, 8));
                if (l15 == 0) {
                    int m = wm * 32 + (vi >> 2) * 16 + quad * 4 + (vi & 3);
                    atomicMin(&v0u[m], __float_as_uint(v));
                }
            }
            __syncthreads();
#pragma unroll
            for (int ms = 0; ms < 2; ++ms)
#pragma unroll
                for (int r = 0; r < 4; ++r)
                    vl[ms][r] = __uint_as_float(v0u[wm*32 + ms*16 + quad*4 + r]) + WWIN;
        }
    }
}

// ---- Rescore candidates exactly (np chain), lexicographic (s, n) min per token ----
__global__ void k_rescore(const float* __restrict__ z, const float* __restrict__ emb,
                          const float* __restrict__ e2g, const float* __restrict__ z2g,
                          const unsigned* __restrict__ list,
                          const unsigned* __restrict__ gcount, unsigned lcap,
                          unsigned long long* __restrict__ keys) {
    unsigned cnt = *gcount; if (cnt > lcap) cnt = lcap;
    unsigned stride = gridDim.x * blockDim.x;
    for (unsigned i = blockIdx.x * blockDim.x + threadIdx.x; i < cnt; i += stride) {
        unsigned e   = list[i];
        unsigned tok = e >> 12, n = e & 4095u;
        const float* zrow = z + (size_t)tok * DDIM;
        const float* erow = emb + (size_t)n * DDIM;
        float a = 0.f;
#pragma unroll
        for (int j = 0; j < DDIM; ++j) a = fmaf(zrow[j] + zrow[j], erow[j], a);
        float s = (z2g[tok] + e2g[n]) - a;   // two fp32 roundings, exactly as np
        unsigned long long key = ((unsigned long long)__float_as_uint(s) << 32)
                               | (unsigned long long)n;
        atomicMin(&keys[tok], key);
    }
}

// ---- Output: indices, quantized gather, loss ----
__global__ __launch_bounds__(256) void k_out(
    const float* __restrict__ z, const float* __restrict__ emb,
    const unsigned long long* __restrict__ keys,
    float* __restrict__ out, double* __restrict__ lossacc) {
    __shared__ int bidx_s[MB];
    __shared__ float red[256];
    const int tid = threadIdx.x;
    const size_t tok0 = (size_t)blockIdx.x * MB;
    if (tid < MB) {
        int nstar = (int)(keys[tok0 + tid] & 0xffffffffULL);
        bidx_s[tid] = nstar;
        out[IDXOFF + tok0 + tid] = (float)nstar;
    }
    __syncthreads();
    float lsum = 0.f;
    const size_t obase = tok0 * DDIM;
#pragma unroll
    for (int it = 0; it < 8; ++it) {
        int f  = it * 256 + tid;    // 0..2047 float4 slots
        int tt = f >> 4, cc = f & 15;
        int idx = bidx_s[tt];
        float4 qv = ((const float4*)(emb + (size_t)idx * DDIM))[cc];
        float4 zv = ((const float4*)(z + obase))[f];
        ((float4*)(out + obase))[f] = qv;
        float dx = qv.x - zv.x, dy = qv.y - zv.y;
        float dz = qv.z - zv.z, dw = qv.w - zv.w;
        lsum += dx * dx + dy * dy + dz * dz + dw * dw;
    }
    red[tid] = lsum;
    __syncthreads();
    for (int s = 128; s > 0; s >>= 1) {
        if (tid < s) red[tid] += red[tid + s];
        __syncthreads();
    }
    if (tid == 0) atomicAdd(lossacc, (double)red[0]);
}

__global__ void k_fin(const double* __restrict__ lossacc, float* __restrict__ out) {
    out[LOSSOFF] = (float)(2.0 * (*lossacc) / (double)(NTOK * DDIM));
}

extern "C" void kernel_launch(void* const* d_in, const int* in_sizes, int n_in,
                              void* d_out, int out_size, void* d_ws, size_t ws_size,
                              hipStream_t stream) {
    const float* z   = (const float*)d_in[0];   // [16,4096,64] fp32
    const float* emb = (const float*)d_in[1];   // [4096,64] fp32
    float* out = (float*)d_out;

    char* ws = (char*)d_ws;
    float*              e2g     = (float*)(ws + OFF_E2);
    unsigned short*     ehg     = (unsigned short*)(ws + OFF_EH);
    unsigned short*     elg     = (unsigned short*)(ws + OFF_EL);
    float*              z2g     = (float*)(ws + OFF_Z2);
    unsigned long long* keys    = (unsigned long long*)(ws + OFF_KEYS);
    double*             lossacc = (double*)(ws + OFF_MISC);
    unsigned*           gcount  = (unsigned*)(ws + OFF_MISC + 8);
    unsigned*           list    = (unsigned*)(ws + OFF_LIST);
    unsigned lcap = 0;
    if (ws_size > OFF_LIST + 16) {
        size_t c = (ws_size - OFF_LIST) / 4;
        lcap = (c > 8000000u) ? 8000000u : (unsigned)c;
    }

    hipLaunchKernelGGL(k_init, dim3(NTOK / 256), dim3(256), 0, stream, keys, lossacc, gcount);
    hipLaunchKernelGGL(k_prep, dim3(16), dim3(256), 0, stream, emb, e2g, ehg, elg);
    hipLaunchKernelGGL(k_vq, dim3(NTOK / MB), dim3(512), 0, stream,
                       z, e2g, ehg, elg, z2g, list, gcount, lcap);
    hipLaunchKernelGGL(k_rescore, dim3(256), dim3(256), 0, stream,
                       z, emb, e2g, z2g, list, gcount, lcap, keys);
    hipLaunchKernelGGL(k_out, dim3(NTOK / MB), dim3(256), 0, stream, z, emb, keys, out, lossacc);
    hipLaunchKernelGGL(k_fin, dim3(1), dim3(1), 0, stream, lossacc, out);
}

// Round 7
// 376.884 us; speedup vs baseline: 2.8043x; 2.8043x over previous
//
#include <hip/hip_runtime.h>

// Problem constants
#define NTOK 65536          // B*S tokens
#define DDIM 64             // embedding dim
#define KCB  4096           // codebook size
#define MB   128            // tokens per block
#define NCH  128            // codes per staged chunk
#define NCHUNKS (KCB / NCH) // 32
#define ESTR 72             // padded LDS row stride (bf16 elems); 144B rows, 16B-aligned
#define LCAP 3072           // per-block candidate capacity (expect ~135)
#define WWIN 4.0e-5f        // rescore window >= 2*(ulp(<256) + mfma-vs-chain err)
#define IDXOFF  (NTOK * DDIM)
#define LOSSOFF (NTOK * DDIM + NTOK)

typedef __bf16 bf16x8 __attribute__((ext_vector_type(8)));
typedef float  f32x4  __attribute__((ext_vector_type(4)));

__device__ __forceinline__ float opaque(float x) { asm volatile("" : "+v"(x)); return x; }

// numpy pairwise sum of squares, n=64
__device__ __forceinline__ float np_sumsq64(const float* __restrict__ v) {
    float r[8];
#pragma unroll
    for (int j = 0; j < 8; ++j) r[j] = opaque(v[j] * v[j]);
#pragma unroll
    for (int i = 1; i < 8; ++i)
#pragma unroll
        for (int j = 0; j < 8; ++j) r[j] += opaque(v[8 * i + j] * v[8 * i + j]);
    return ((r[0] + r[1]) + (r[2] + r[3])) + ((r[4] + r[5]) + (r[6] + r[7]));
}

__device__ __forceinline__ unsigned short bf16rne(float x) {
    unsigned u = __float_as_uint(x);
    return (unsigned short)((u + 0x7fffu + ((u >> 16) & 1u)) >> 16);
}
__device__ __forceinline__ float bf16tof(unsigned short h) {
    return __uint_as_float(((unsigned)h) << 16);
}

// ---- Prep: e2 (np pairwise) + split-bf16 codebook + zero loss ----
__global__ void k_prep(const float* __restrict__ emb, float* __restrict__ e2,
                       unsigned short* __restrict__ eh, unsigned short* __restrict__ el,
                       double* __restrict__ lossacc) {
    int k = blockIdx.x * blockDim.x + threadIdx.x;
    if (k == 0) *lossacc = 0.0;
    if (k >= KCB) return;
    float row[DDIM];
    const float4* r4 = (const float4*)(emb + (size_t)k * DDIM);
#pragma unroll
    for (int i = 0; i < DDIM / 4; ++i) {
        float4 v = r4[i];
        row[4*i+0] = v.x; row[4*i+1] = v.y; row[4*i+2] = v.z; row[4*i+3] = v.w;
    }
    e2[k] = np_sumsq64(row);
#pragma unroll
    for (int j = 0; j < DDIM; ++j) {
        unsigned short h = bf16rne(row[j]);
        unsigned short l = bf16rne(row[j] - bf16tof(h));
        eh[(size_t)k * DDIM + j] = h;
        el[(size_t)k * DDIM + j] = l;
    }
}

// ---- Main: A(z) in VGPRs whole-kernel; two MFMA sweeps; LDS list; fused exact rescore ----
// 512 thr = 8 waves; wm = w>>1 (0..3): 32-token group; wn = w&1: 64-code half of NCH=128.
// Score: m~ = (2z)@e^T via 3 bf16-split MFMA products; shat = fl(fl(z2+e2)-m~).
// Sweep 0 -> v0 per token; sweep 1 -> append shat<=v0+W to LDS list; exact np-chain
// rescore of candidates -> lexicographic (s,n) min == np first-occurrence argmin.
__global__ __launch_bounds__(512) __attribute__((amdgpu_waves_per_eu(4, 4)))
void k_vq(const float* __restrict__ z, const float* __restrict__ emb,
          const float* __restrict__ e2g,
          const unsigned short* __restrict__ ehg, const unsigned short* __restrict__ elg,
          float* __restrict__ out, double* __restrict__ lossacc) {
    __shared__ alignas(16) unsigned short esh[NCH * ESTR], esl[NCH * ESTR];  // 36 KB
    __shared__ float e2t[NCH];
    __shared__ float z2s[MB];
    __shared__ unsigned v0u[MB];
    __shared__ unsigned long long keys[MB];
    __shared__ unsigned list[LCAP];          // 12 KB
    __shared__ int lcnt;
    __shared__ float red[512];
    __shared__ int bidx_s[MB];

    const int tid  = threadIdx.x;
    const int lane = tid & 63;
    const int l15  = lane & 15;
    const int quad = lane >> 4;
    const int w    = tid >> 6;
    const int wm   = w >> 1;    // 0..3 : 32-token group
    const int wn   = w & 1;     // 0..1 : 64-code half
    const int tok0 = blockIdx.x * MB;
    const size_t zbase = (size_t)tok0 * DDIM;

    if (tid < MB) { v0u[tid] = 0x7f800000u; keys[tid] = 0xFFFFFFFFFFFFFFFFull; }
    if (tid == 0) lcnt = 0;

    // ---- Build A-fragments (2*z, split bf16) straight from global into VGPRs ----
    // A[m=l15][k=quad*8+j]; frag kh covers k in [kh*32, kh*32+32).
    bf16x8 Ah[2][2], Al[2][2];   // [ms][kh]
#pragma unroll
    for (int ms = 0; ms < 2; ++ms) {
        const float* p = z + zbase + (size_t)(wm * 32 + ms * 16 + l15) * DDIM + quad * 8;
#pragma unroll
        for (int kh = 0; kh < 2; ++kh) {
            float4 u0 = *(const float4*)(p + kh * 32);
            float4 u1 = *(const float4*)(p + kh * 32 + 4);
            float d[8] = {u0.x + u0.x, u0.y + u0.y, u0.z + u0.z, u0.w + u0.w,
                          u1.x + u1.x, u1.y + u1.y, u1.z + u1.z, u1.w + u1.w};
            union { bf16x8 v; unsigned short u[8]; } th, tl;
#pragma unroll
            for (int j = 0; j < 8; ++j) {
                unsigned short h = bf16rne(d[j]);
                th.u[j] = h;
                tl.u[j] = bf16rne(d[j] - bf16tof(h));
            }
            Ah[ms][kh] = th.v;
            Al[ms][kh] = tl.v;
        }
    }

    // z2 per token: exact np pairwise (from global z)
    if (tid < MB) {
        float row[DDIM];
        const float4* zr4 = (const float4*)(z + zbase + (size_t)tid * DDIM);
#pragma unroll
        for (int i = 0; i < DDIM / 4; ++i) {
            float4 v = zr4[i];
            row[4*i+0] = v.x; row[4*i+1] = v.y; row[4*i+2] = v.z; row[4*i+3] = v.w;
        }
        z2s[tid] = np_sumsq64(row);
    }
    __syncthreads();

    f32x4 z2l[2];
#pragma unroll
    for (int ms = 0; ms < 2; ++ms)
        z2l[ms] = *(const f32x4*)(z2s + wm * 32 + ms * 16 + quad * 4);

    float vrun[8];
#pragma unroll
    for (int i = 0; i < 8; ++i) vrun[i] = 3.0e38f;
    float vl[2][4];

#pragma unroll 1
    for (int phase = 0; phase < 2; ++phase) {
#pragma unroll 1
        for (int ch = 0; ch < NCHUNKS; ++ch) {
            const int n0 = ch * NCH;
            __syncthreads();   // prior chunk frag reads done
#pragma unroll
            for (int it = 0; it < 4; ++it) {
                int f  = it * 512 + tid;    // 0..2047 ushort4 slots (128 rows * 16)
                int rr = f >> 4, c4 = f & 15;
                *(ushort4*)(esh + rr * ESTR + c4 * 4) =
                    ((const ushort4*)(ehg + (size_t)(n0 + rr) * DDIM))[c4];
                *(ushort4*)(esl + rr * ESTR + c4 * 4) =
                    ((const ushort4*)(elg + (size_t)(n0 + rr) * DDIM))[c4];
            }
            if (tid < NCH) e2t[tid] = e2g[n0 + tid];
            __syncthreads();

            // two groups of 2 n-subtiles; B-frags buffered per group (32 VGPR)
#pragma unroll
            for (int g = 0; g < 2; ++g) {
                bf16x8 Bh[2][2], Bl[2][2];   // [ns2][kh]
#pragma unroll
                for (int ns2 = 0; ns2 < 2; ++ns2) {
                    int nl = wn * 64 + (g * 2 + ns2) * 16 + l15;
                    const unsigned short* pb = esh + nl * ESTR + quad * 8;
                    const unsigned short* pc = esl + nl * ESTR + quad * 8;
                    Bh[ns2][0] = *(const bf16x8*)(pb);
                    Bh[ns2][1] = *(const bf16x8*)(pb + 32);
                    Bl[ns2][0] = *(const bf16x8*)(pc);
                    Bl[ns2][1] = *(const bf16x8*)(pc + 32);
                }
#pragma unroll
                for (int ns2 = 0; ns2 < 2; ++ns2) {
                    int nl  = wn * 64 + (g * 2 + ns2) * 16 + l15;
                    int n   = n0 + nl;
                    float e2v = e2t[nl];
#pragma unroll
                    for (int ms = 0; ms < 2; ++ms) {
                        f32x4 a0 = {0.f, 0.f, 0.f, 0.f}, a1 = {0.f, 0.f, 0.f, 0.f};
                        a0 = __builtin_amdgcn_mfma_f32_16x16x32_bf16(Ah[ms][0], Bh[ns2][0], a0, 0, 0, 0);
                        a1 = __builtin_amdgcn_mfma_f32_16x16x32_bf16(Ah[ms][1], Bh[ns2][1], a1, 0, 0, 0);
                        a0 = __builtin_amdgcn_mfma_f32_16x16x32_bf16(Ah[ms][0], Bl[ns2][0], a0, 0, 0, 0);
                        a1 = __builtin_amdgcn_mfma_f32_16x16x32_bf16(Ah[ms][1], Bl[ns2][1], a1, 0, 0, 0);
                        a0 = __builtin_amdgcn_mfma_f32_16x16x32_bf16(Al[ms][0], Bh[ns2][0], a0, 0, 0, 0);
                        a1 = __builtin_amdgcn_mfma_f32_16x16x32_bf16(Al[ms][1], Bh[ns2][1], a1, 0, 0, 0);
#pragma unroll
                        for (int r = 0; r < 4; ++r) {
                            float shat = (z2l[ms][r] + e2v) - (a0[r] + a1[r]);
                            if (phase == 0) {
                                vrun[ms * 4 + r] = fminf(vrun[ms * 4 + r], shat);
                            } else if (shat <= vl[ms][r]) {
                                int m = wm * 32 + ms * 16 + quad * 4 + r;
                                int idx = atomicAdd(&lcnt, 1);
                                if (idx < LCAP)
                                    list[idx] = ((unsigned)m << 12) | (unsigned)n;
                            }
                        }
                    }
                }
            }
        }
        if (phase == 0) {
            // min over the 16 n-lanes (l15 dim), then LDS atomicMin per token
#pragma unroll
            for (int vi = 0; vi < 8; ++vi) {
                float v = vrun[vi];
                v = fminf(v, __shfl_xor(v, 1));
                v = fminf(v, __shfl_xor(v, 2));
                v = fminf(v, __shfl_xor(v, 4));
                v = fminf(v, __shfl_xor(v, 8));
                if (l15 == 0) {
                    int m = wm * 32 + (vi >> 2) * 16 + quad * 4 + (vi & 3);
                    atomicMin(&v0u[m], __float_as_uint(v));
                }
            }
            __syncthreads();
#pragma unroll
            for (int ms = 0; ms < 2; ++ms)
#pragma unroll
                for (int r = 0; r < 4; ++r)
                    vl[ms][r] = __uint_as_float(v0u[wm*32 + ms*16 + quad*4 + r]) + WWIN;
        }
    }
    __syncthreads();   // list complete

    // ---- Exact rescore (np chain), lexicographic (s, n) min per token ----
    int cnt = lcnt; if (cnt > LCAP) cnt = LCAP;
    for (int i = tid; i < cnt; i += 512) {
        unsigned e = list[i];
        int m = (int)(e >> 12), n = (int)(e & 4095u);
        const float* zrow = z + zbase + (size_t)m * DDIM;
        const float* erow = emb + (size_t)n * DDIM;
        float a = 0.f;
#pragma unroll
        for (int j = 0; j < DDIM; ++j) a = fmaf(zrow[j] + zrow[j], erow[j], a);
        float s = (z2s[m] + e2g[n]) - a;   // two fp32 roundings, exactly as np
        unsigned long long key = ((unsigned long long)__float_as_uint(s) << 32)
                               | (unsigned long long)(unsigned)n;
        atomicMin(&keys[m], key);
    }
    __syncthreads();

    if (tid < MB) {
        int nstar = (int)(keys[tid] & 0xffffffffULL);
        bidx_s[tid] = nstar;
        out[IDXOFF + tok0 + tid] = (float)nstar;
    }
    __syncthreads();

    // ---- Epilogue: quantized gather-write (coalesced float4) + loss ----
    float lsum = 0.f;
#pragma unroll
    for (int it = 0; it < 4; ++it) {
        int f  = it * 512 + tid;    // 0..2047 float4 slots
        int tt = f >> 4, cc = f & 15;
        int idx = bidx_s[tt];
        float4 qv = ((const float4*)(emb + (size_t)idx * DDIM))[cc];
        float4 zv = ((const float4*)(z + zbase))[f];
        ((float4*)(out + zbase))[f] = qv;
        float dx = qv.x - zv.x, dy = qv.y - zv.y;
        float dz = qv.z - zv.z, dw = qv.w - zv.w;
        lsum += dx * dx + dy * dy + dz * dz + dw * dw;
    }
    red[tid] = lsum;
    __syncthreads();
    for (int s = 256; s > 0; s >>= 1) {
        if (tid < s) red[tid] += red[tid + s];
        __syncthreads();
    }
    if (tid == 0) atomicAdd(lossacc, (double)red[0]);
}

__global__ void k_fin(const double* __restrict__ lossacc, float* __restrict__ out) {
    out[LOSSOFF] = (float)(2.0 * (*lossacc) / (double)(NTOK * DDIM));
}

extern "C" void kernel_launch(void* const* d_in, const int* in_sizes, int n_in,
                              void* d_out, int out_size, void* d_ws, size_t ws_size,
                              hipStream_t stream) {
    const float* z   = (const float*)d_in[0];   // [16,4096,64] fp32
    const float* emb = (const float*)d_in[1];   // [4096,64] fp32
    float* out = (float*)d_out;

    char* ws = (char*)d_ws;
    float*          e2g     = (float*)(ws);                    // 16 KB
    unsigned short* ehg     = (unsigned short*)(ws + 16384);   // 512 KB
    unsigned short* elg     = (unsigned short*)(ws + 540672);  // 512 KB
    double*         lossacc = (double*)(ws + 1064960);

    hipLaunchKernelGGL(k_prep, dim3(16), dim3(256), 0, stream, emb, e2g, ehg, elg, lossacc);
    hipLaunchKernelGGL(k_vq, dim3(NTOK / MB), dim3(512), 0, stream,
                       z, emb, e2g, ehg, elg, out, lossacc);
    hipLaunchKernelGGL(k_fin, dim3(1), dim3(1), 0, stream, lossacc, out);
}